// Round 4
// baseline (96.260 us; speedup 1.0000x reference)
//
#include <hip/hip_runtime.h>

#define N 32768
#define P 8192
#define MX 8                          // x-values per wave (wave-uniform)
#define XG 4                          // x-groups per block
#define PH 2                          // pattern halves
#define THREADS (XG * PH * 64)        // 512
#define XPB (XG * MX)                 // 32 x per block
#define NBLK (N / XPB)                // 1024
#define PAIRS (P / 2)                 // 4096 pattern-pairs
#define PAIRS_PER_PH (PAIRS / PH)     // 2048
#define ITERS (PAIRS_PER_PH / 64)     // 32 — fully unrolled

// f = log2(e)/(2*sigma^2), sigma^2 = 1.44; per-x |x|^2 cancels in num/den.
#define RBF_F 0.50093577808645257f

typedef float v2f __attribute__((ext_vector_type(2)));

static __device__ __forceinline__ float fast_exp2(float x) {
#if __has_builtin(__builtin_amdgcn_exp2f)
    return __builtin_amdgcn_exp2f(x);
#else
    return exp2f(x);
#endif
}

// Pair-interleaved constants for pattern pair q = (2q, 2q+1):
//   c[2q]   = { c0(2q), c0(2q+1), c1(2q), c1(2q+1) }
//   c[2q+1] = { c2(2q), c2(2q+1), w(2q),  w(2q+1)  }
__global__ void prep_kernel(const float* __restrict__ pat,
                            const float* __restrict__ w2,
                            float4* __restrict__ c) {
    int q = blockIdx.x * blockDim.x + threadIdx.x;
    if (q < P / 2) {
        float p00 = pat[4 * q + 0], p01 = pat[4 * q + 1];
        float p10 = pat[4 * q + 2], p11 = pat[4 * q + 3];
        float4 a, b;
        a.x = 2.0f * RBF_F * p00;  a.y = 2.0f * RBF_F * p10;
        a.z = 2.0f * RBF_F * p01;  a.w = 2.0f * RBF_F * p11;
        b.x = -RBF_F * (p00 * p00 + p01 * p01);
        b.y = -RBF_F * (p10 * p10 + p11 * p11);
        b.z = w2[2 * q];           b.w = w2[2 * q + 1];
        c[2 * q]     = a;
        c[2 * q + 1] = b;
    }
}

// Port-cycle budget per j-body (wave64, SIMD32 datapath):
//   dot   2 v2f fma × 8x          = 64 cy
//   accum 1 v2f add + 1 v2f fma ×8= 64 cy
//   exp   16 × v_exp_f32 (1/8 rt) = 256 cy   ← 61%, irreducible
// Full unroll + imm-offset loads target the ~38 cy/body addressing tax.
__global__ __launch_bounds__(THREADS, 4) void
rbf_kernel(const float* __restrict__ X,
           const float4* __restrict__ c,
           float* __restrict__ out) {
    const int t    = threadIdx.x;
    const int lane = t & 63;
    const int w    = __builtin_amdgcn_readfirstlane(t >> 6);  // 0..7
    const int xg   = w >> 1;
    const int ph   = w & 1;

    // MX wave-uniform x-values, hoisted as persistent splat pairs
    const int xb = blockIdx.x * XPB + xg * MX;
    const float2* Xp = (const float2*)X;
    v2f xs0[MX], xs1[MX];
#pragma unroll
    for (int i = 0; i < MX; ++i) {
        float2 xv = Xp[xb + i];
        xs0[i] = (v2f){xv.x, xv.x};
        xs1[i] = (v2f){xv.y, xv.y};
    }

    v2f num2[MX], den2[MX];
#pragma unroll
    for (int i = 0; i < MX; ++i) {
        num2[i] = (v2f){0.f, 0.f};
        den2[i] = (v2f){0.f, 0.f};
    }

    // per-lane base; per-j offsets are compile-time (SGPR bump + imm)
    const float4* __restrict__ C4w =
        c + (size_t)ph * (2 * PAIRS_PER_PH) + 2 * lane;

#pragma unroll
    for (int j = 0; j < ITERS; ++j) {
        float4 a = C4w[(j << 7)];        // (j<<7)+2*lane elements from c
        float4 b = C4w[(j << 7) + 1];
#pragma unroll
        for (int i = 0; i < MX; ++i) {
            // arg for patterns (2q, 2q+1) at x_i — direct register pairs
            v2f tt = __builtin_elementwise_fma((v2f){a.x, a.y}, xs0[i],
                                               (v2f){b.x, b.y});
            tt = __builtin_elementwise_fma((v2f){a.z, a.w}, xs1[i], tt);
            v2f k = (v2f){fast_exp2(tt.x), fast_exp2(tt.y)};
            den2[i] += k;
            num2[i] = __builtin_elementwise_fma(k, (v2f){b.z, b.w}, num2[i]);
        }
    }

    // fold pattern-pair halves, then 6-step butterfly across the wave
    float num[MX], den[MX];
#pragma unroll
    for (int i = 0; i < MX; ++i) {
        num[i] = num2[i].x + num2[i].y;
        den[i] = den2[i].x + den2[i].y;
    }
#pragma unroll
    for (int m = 1; m < 64; m <<= 1) {
#pragma unroll
        for (int i = 0; i < MX; ++i) {
            num[i] += __shfl_xor(num[i], m, 64);
            den[i] += __shfl_xor(den[i], m, 64);
        }
    }

    __shared__ float red[XG][PH][MX][2];
    if (lane == 0) {
#pragma unroll
        for (int i = 0; i < MX; ++i) {
            red[xg][ph][i][0] = num[i];
            red[xg][ph][i][1] = den[i];
        }
    }
    __syncthreads();

    if (t < XPB) {
        int g = t >> 3, xi = t & 7;   // t / MX, t % MX (MX=8)
        float nn = red[g][0][xi][0] + red[g][1][xi][0];
        float dd = red[g][0][xi][1] + red[g][1][xi][1];
        out[blockIdx.x * XPB + t] = nn / dd;
    }
}

extern "C" void kernel_launch(void* const* d_in, const int* in_sizes, int n_in,
                              void* d_out, int out_size, void* d_ws, size_t ws_size,
                              hipStream_t stream) {
    const float* X   = (const float*)d_in[0];   // [32768, 2]
    const float* pat = (const float*)d_in[1];   // [8192, 2]
    const float* w2  = (const float*)d_in[2];   // [8192]
    float* out = (float*)d_out;                 // [32768]
    float4* c = (float4*)d_ws;                  // 8192 * 16 B = 128 KB

    prep_kernel<<<(P / 2 + 255) / 256, 256, 0, stream>>>(pat, w2, c);
    rbf_kernel<<<NBLK, THREADS, 0, stream>>>(X, c, out);
}

// Round 5
// 95.163 us; speedup vs baseline: 1.0115x; 1.0115x over previous
//
#include <hip/hip_runtime.h>

#define N 32768
#define P 8192
#define MX 8                          // x-values per wave (wave-uniform)
#define XG 4                          // x-groups per block
#define PH 2                          // pattern halves
#define THREADS (XG * PH * 64)        // 512
#define XPB (XG * MX)                 // 32 x per block
#define NBLK (N / XPB)                // 1024
#define PAIRS (P / 2)                 // 4096 pattern-pairs
#define PAIRS_PER_PH (PAIRS / PH)     // 2048
#define ITERS (PAIRS_PER_PH / 64)     // 32

// f = log2(e)/(2*sigma^2), sigma^2 = 1.44; per-x |x|^2 cancels in num/den.
#define RBF_F 0.50093577808645257f

typedef float v2f __attribute__((ext_vector_type(2)));

static __device__ __forceinline__ float fast_exp2(float x) {
#if __has_builtin(__builtin_amdgcn_exp2f)
    return __builtin_amdgcn_exp2f(x);
#else
    return exp2f(x);
#endif
}

// Pair-interleaved constants for pattern pair q = (2q, 2q+1):
//   c[2q]   = { c0(2q), c0(2q+1), c1(2q), c1(2q+1) }
//   c[2q+1] = { c2(2q), c2(2q+1), w(2q),  w(2q+1)  }
__global__ void prep_kernel(const float* __restrict__ pat,
                            const float* __restrict__ w2,
                            float4* __restrict__ c) {
    int q = blockIdx.x * blockDim.x + threadIdx.x;
    if (q < P / 2) {
        float p00 = pat[4 * q + 0], p01 = pat[4 * q + 1];
        float p10 = pat[4 * q + 2], p11 = pat[4 * q + 3];
        float4 a, b;
        a.x = 2.0f * RBF_F * p00;  a.y = 2.0f * RBF_F * p10;
        a.z = 2.0f * RBF_F * p01;  a.w = 2.0f * RBF_F * p11;
        b.x = -RBF_F * (p00 * p00 + p01 * p01);
        b.y = -RBF_F * (p10 * p10 + p11 * p11);
        b.z = w2[2 * q];           b.w = w2[2 * q + 1];
        c[2 * q]     = a;
        c[2 * q + 1] = b;
    }
}

// Port-cycle budget per j-body (wave64, SIMD32 datapath, fully serialized):
//   dot    2 v_pk_fma × 8x              =  64 cy
//   accum  (v_pk_add + v_pk_fma) × 8x   =  64 cy
//   exp    16 × v_exp_f32 (4 lanes/cy)  = 256 cy   <- 61%, irreducible
// 4-deep in-place reload (no ring math, no buffer copies) targets the
// ~38 cy/body addressing tax measured in r3.
#define BODY(aa, bb)                                                          \
    _Pragma("unroll")                                                         \
    for (int i = 0; i < MX; ++i) {                                            \
        v2f tt = __builtin_elementwise_fma((v2f){(aa).x, (aa).y}, xs0[i],     \
                                           (v2f){(bb).x, (bb).y});            \
        tt = __builtin_elementwise_fma((v2f){(aa).z, (aa).w}, xs1[i], tt);    \
        v2f k = (v2f){fast_exp2(tt.x), fast_exp2(tt.y)};                      \
        den2[i] += k;                                                         \
        num2[i] = __builtin_elementwise_fma(k, (v2f){(bb).z, (bb).w},         \
                                            num2[i]);                        \
    }

__global__ __launch_bounds__(THREADS, 4) void
rbf_kernel(const float* __restrict__ X,
           const float4* __restrict__ c,
           float* __restrict__ out) {
    const int t    = threadIdx.x;
    const int lane = t & 63;
    const int w    = __builtin_amdgcn_readfirstlane(t >> 6);  // 0..7
    const int xg   = w >> 1;
    const int ph   = w & 1;

    // MX wave-uniform x-values, hoisted as persistent splat pairs
    const int xb = blockIdx.x * XPB + xg * MX;
    const float2* Xp = (const float2*)X;
    v2f xs0[MX], xs1[MX];
#pragma unroll
    for (int i = 0; i < MX; ++i) {
        float2 xv = Xp[xb + i];
        xs0[i] = (v2f){xv.x, xv.x};
        xs1[i] = (v2f){xv.y, xv.y};
    }

    v2f num2[MX], den2[MX];
#pragma unroll
    for (int i = 0; i < MX; ++i) {
        num2[i] = (v2f){0.f, 0.f};
        den2[i] = (v2f){0.f, 0.f};
    }

    // per-lane stream base; j-stride is 128 float4 (64 lanes x 2)
    const float4* __restrict__ Cp =
        c + (size_t)ph * (2 * PAIRS_PER_PH) + 2 * lane;

    // preload bodies j = 0..3 into named buffers (no runtime indexing)
    float4 A0 = Cp[0],   B0 = Cp[1];
    float4 A1 = Cp[128], B1 = Cp[129];
    float4 A2 = Cp[256], B2 = Cp[257];
    float4 A3 = Cp[384], B3 = Cp[385];

    // steady state: consume body j+k, reload its registers with body j+4+k.
    // Prefetch distance ~3 bodies (~1200 port-cycles) covers L2 latency.
    for (int j = 0; j + 8 <= ITERS; j += 4) {
        const float4* Cn = Cp + (j + 4) * 128;
        BODY(A0, B0)  A0 = Cn[0];   B0 = Cn[1];
        BODY(A1, B1)  A1 = Cn[128]; B1 = Cn[129];
        BODY(A2, B2)  A2 = Cn[256]; B2 = Cn[257];
        BODY(A3, B3)  A3 = Cn[384]; B3 = Cn[385];
    }
    // tail: last 4 bodies, nothing left to prefetch
    BODY(A0, B0)
    BODY(A1, B1)
    BODY(A2, B2)
    BODY(A3, B3)

    // fold pattern-pair halves, then 6-step butterfly across the wave
    float num[MX], den[MX];
#pragma unroll
    for (int i = 0; i < MX; ++i) {
        num[i] = num2[i].x + num2[i].y;
        den[i] = den2[i].x + den2[i].y;
    }
#pragma unroll
    for (int m = 1; m < 64; m <<= 1) {
#pragma unroll
        for (int i = 0; i < MX; ++i) {
            num[i] += __shfl_xor(num[i], m, 64);
            den[i] += __shfl_xor(den[i], m, 64);
        }
    }

    __shared__ float red[XG][PH][MX][2];
    if (lane == 0) {
#pragma unroll
        for (int i = 0; i < MX; ++i) {
            red[xg][ph][i][0] = num[i];
            red[xg][ph][i][1] = den[i];
        }
    }
    __syncthreads();

    if (t < XPB) {
        int g = t >> 3, xi = t & 7;   // t / MX, t % MX (MX=8)
        float nn = red[g][0][xi][0] + red[g][1][xi][0];
        float dd = red[g][0][xi][1] + red[g][1][xi][1];
        out[blockIdx.x * XPB + t] = nn / dd;
    }
}

extern "C" void kernel_launch(void* const* d_in, const int* in_sizes, int n_in,
                              void* d_out, int out_size, void* d_ws, size_t ws_size,
                              hipStream_t stream) {
    const float* X   = (const float*)d_in[0];   // [32768, 2]
    const float* pat = (const float*)d_in[1];   // [8192, 2]
    const float* w2  = (const float*)d_in[2];   // [8192]
    float* out = (float*)d_out;                 // [32768]
    float4* c = (float4*)d_ws;                  // 8192 * 16 B = 128 KB

    prep_kernel<<<(P / 2 + 255) / 256, 256, 0, stream>>>(pat, w2, c);
    rbf_kernel<<<NBLK, THREADS, 0, stream>>>(X, c, out);
}